// Round 6
// baseline (5787.966 us; speedup 1.0000x reference)
//
#include <hip/hip_runtime.h>

// Seq2SeqLSTMForecaster on MI355X — round 6.
//  - kA/kB2: 1024 thr, 4-way split-k, dual-gate (16 waves/CU for barrier/LDS
//            overlap; VALU + LDS-instr counts unchanged vs round 5).
//  - kX    : fp32 tiled GEMM (unchanged), CL=42 so X1/ys0T stay L3-resident.
//  - kD    : restructured decoder:
//            * x-term moved to act phase (act threads sum rp directly) ->
//              head overlaps L0 dot, 4 barriers/step instead of 6.
//            * head weights: k<64 in registers (64/thread), k>=64 from LDS
//              rows [hid][68] read as lane-spread b128 (even bank spread).
//            * epilogue computes the final head after the loop.

#define B_    1024
#define T_    672
#define H_    128
#define G_    512      // 4*H
#define TGT_  96
#define NBLK_ 256

__device__ __forceinline__ float sigm(float x)   { return 1.f / (1.f + __expf(-x)); }
__device__ __forceinline__ float tanh_f(float x) { return 1.f - 2.f / (1.f + __expf(2.f * x)); }

// ---------------------------------------------------------------- prep ------
struct PrepArgs {
    const float* t_src[4];   // eWhh0, eWih1, eWhh1, dWhh0 -> [128,512]
    float*       t_dst[4];
    const float* d1x;  const float* d1h;  float* pack;   // dec L1 4-wide pack
};

__global__ void kPrep(PrepArgs a) {
    const int m = blockIdx.x;
    if (m < 4) {
        for (int i = threadIdx.x; i < G_ * H_; i += blockDim.x) {
            const int j = i >> 7, k = i & 127;
            a.t_dst[m][k * G_ + j] = a.t_src[m][i];
        }
    } else {
        // pack[(k*256 + j2)*4] = {Wih1[j2][k], Whh1[j2][k], Wih1[j2+256][k], Whh1[j2+256][k]}
        for (int i = threadIdx.x; i < H_ * 256; i += blockDim.x) {
            const int k = i >> 8, j2 = i & 255;
            float* p = a.pack + ((size_t)k * 256 + j2) * 4;
            p[0] = a.d1x[j2 * H_ + k];
            p[1] = a.d1h[j2 * H_ + k];
            p[2] = a.d1x[(j2 + 256) * H_ + k];
            p[3] = a.d1h[(j2 + 256) * H_ + k];
        }
    }
}

// --------------------------------- enc L0 (1024 thr, 4-way k, dual-gate) ----
__global__ __launch_bounds__(1024, 4) void kA(
    const float* __restrict__ feat,   // [B,T]
    const float* __restrict__ whhT,   // [128,512] enc_Whh0^T
    const float* __restrict__ wih0,   // [512]
    const float* __restrict__ bias,   // [512]
    float* __restrict__ ys0T,         // [CL][128][1024] k-major
    float* __restrict__ hS, float* __restrict__ cS,
    int t0, int CL)
{
    __shared__ __align__(16) float h_sh[H_ * 4];     // [hid][bb]
    __shared__ __align__(16) float zp[4 * 2048];     // [kq][batch][gate]
    __shared__ __align__(16) float f_sh[84 * 4];

    const int tid = threadIdx.x;
    const int j2  = tid & 255;         // gates j2, j2+256
    const int kq  = tid >> 8;          // k-quarter 0..3
    const int B0  = blockIdx.x * 4;

    float w0[32], w1[32];
#pragma unroll
    for (int k = 0; k < 32; k++) {
        w0[k] = whhT[(kq * 32 + k) * G_ + j2];
        w1[k] = whhT[(kq * 32 + k) * G_ + j2 + 256];
    }
    const float wx0 = wih0[j2],       bj0 = bias[j2];
    const float wx1 = wih0[j2 + 256], bj1 = bias[j2 + 256];

    for (int i = tid; i < CL * 4; i += 1024)
        f_sh[i] = feat[(B0 + (i & 3)) * T_ + t0 + (i >> 2)];

    const int hid = tid & 127, bb = (tid >> 7) & 3;
    float c = 0.f;
    if (tid < 512) {
        float hv = 0.f;
        if (t0 != 0) { c = cS[(B0 + bb) * H_ + hid]; hv = hS[(B0 + bb) * H_ + hid]; }
        h_sh[hid * 4 + bb] = hv;
    }
    __syncthreads();

    const float* hb = h_sh + kq * 128;
    for (int dt = 0; dt < CL; dt++) {
        if (tid < 512 && dt > 0)
            ys0T[((size_t)(dt - 1) * H_ + (tid >> 2)) * B_ + B0 + (tid & 3)] = h_sh[tid];

        float a0, a1, a2, a3, e0, e1, e2, e3;
        if (kq == 0) {
            const float4 xv = *(const float4*)&f_sh[dt * 4];
            a0 = __fmaf_rn(xv.x, wx0, bj0); a1 = __fmaf_rn(xv.y, wx0, bj0);
            a2 = __fmaf_rn(xv.z, wx0, bj0); a3 = __fmaf_rn(xv.w, wx0, bj0);
            e0 = __fmaf_rn(xv.x, wx1, bj1); e1 = __fmaf_rn(xv.y, wx1, bj1);
            e2 = __fmaf_rn(xv.z, wx1, bj1); e3 = __fmaf_rn(xv.w, wx1, bj1);
        } else { a0=a1=a2=a3=e0=e1=e2=e3=0.f; }
#pragma unroll
        for (int k = 0; k < 32; k++) {
            const float4 h4 = *(const float4*)&hb[k * 4];   // uniform broadcast
            a0 = __fmaf_rn(h4.x, w0[k], a0); a1 = __fmaf_rn(h4.y, w0[k], a1);
            a2 = __fmaf_rn(h4.z, w0[k], a2); a3 = __fmaf_rn(h4.w, w0[k], a3);
            e0 = __fmaf_rn(h4.x, w1[k], e0); e1 = __fmaf_rn(h4.y, w1[k], e1);
            e2 = __fmaf_rn(h4.z, w1[k], e2); e3 = __fmaf_rn(h4.w, w1[k], e3);
        }
        float* zb = zp + kq * 2048;
        zb[0*G_ + j2] = a0; zb[1*G_ + j2] = a1; zb[2*G_ + j2] = a2; zb[3*G_ + j2] = a3;
        zb[0*G_ + j2+256] = e0; zb[1*G_ + j2+256] = e1; zb[2*G_ + j2+256] = e2; zb[3*G_ + j2+256] = e3;
        __syncthreads();

        if (tid < 512) {
            const int b5 = bb * G_;
            const float zi = zp[b5+hid]        + zp[2048+b5+hid]        + zp[4096+b5+hid]        + zp[6144+b5+hid];
            const float zf = zp[b5+hid+H_]     + zp[2048+b5+hid+H_]     + zp[4096+b5+hid+H_]     + zp[6144+b5+hid+H_];
            const float zg = zp[b5+hid+2*H_]   + zp[2048+b5+hid+2*H_]   + zp[4096+b5+hid+2*H_]   + zp[6144+b5+hid+2*H_];
            const float zo = zp[b5+hid+3*H_]   + zp[2048+b5+hid+3*H_]   + zp[4096+b5+hid+3*H_]   + zp[6144+b5+hid+3*H_];
            c = sigm(zf) * c + sigm(zi) * tanh_f(zg);
            h_sh[hid * 4 + bb] = sigm(zo) * tanh_f(c);
        }
        __syncthreads();
    }
    if (tid < 512) {
        ys0T[((size_t)(CL - 1) * H_ + (tid >> 2)) * B_ + B0 + (tid & 3)] = h_sh[tid];
        hS[(B0 + bb) * H_ + hid] = h_sh[hid * 4 + bb];
        cS[(B0 + bb) * H_ + hid] = c;
    }
}

// ------------------------------------------------- X1 GEMM (fp32 tiled) -----
__global__ __launch_bounds__(256, 3) void kX(
    const float* __restrict__ ys0T,   // [CL][128][1024]
    const float* __restrict__ wT,     // [128][512]
    const float* __restrict__ bias,   // [512]
    float* __restrict__ X1)           // [CL][1024][512]
{
    __shared__ __align__(16) float As[64][132];
    __shared__ __align__(16) float Bs[64][68];

    const int tid = threadIdx.x;
    const int m0 = blockIdx.x * 128;
    const int n0 = blockIdx.y * 64;
    const int dt = blockIdx.z;
    const float* A = ys0T + (size_t)dt * H_ * B_;

    const int tx = tid & 15, ty = tid >> 4;
    float acc[8][4] = {};

#pragma unroll
    for (int ks = 0; ks < 2; ks++) {
        if (ks) __syncthreads();
        for (int t = tid; t < 64 * 32; t += 256) {
            const int r = t >> 5, q = t & 31;
            *(float4*)&As[r][q * 4] = *(const float4*)&A[(size_t)(ks * 64 + r) * B_ + m0 + q * 4];
        }
        for (int t = tid; t < 64 * 16; t += 256) {
            const int r = t >> 4, q = t & 15;
            *(float4*)&Bs[r][q * 4] = *(const float4*)&wT[(size_t)(ks * 64 + r) * G_ + n0 + q * 4];
        }
        __syncthreads();

#pragma unroll 4
        for (int k = 0; k < 64; k++) {
            float av[8];
            *(float4*)&av[0] = *(const float4*)&As[k][ty * 8];
            *(float4*)&av[4] = *(const float4*)&As[k][ty * 8 + 4];
            const float4 bv = *(const float4*)&Bs[k][tx * 4];
#pragma unroll
            for (int i = 0; i < 8; i++) {
                acc[i][0] = __fmaf_rn(av[i], bv.x, acc[i][0]);
                acc[i][1] = __fmaf_rn(av[i], bv.y, acc[i][1]);
                acc[i][2] = __fmaf_rn(av[i], bv.z, acc[i][2]);
                acc[i][3] = __fmaf_rn(av[i], bv.w, acc[i][3]);
            }
        }
    }

    const float4 bvb = *(const float4*)&bias[n0 + tx * 4];
#pragma unroll
    for (int i = 0; i < 8; i++) {
        float4 o;
        o.x = acc[i][0] + bvb.x; o.y = acc[i][1] + bvb.y;
        o.z = acc[i][2] + bvb.z; o.w = acc[i][3] + bvb.w;
        *(float4*)&X1[((size_t)dt * B_ + m0 + ty * 8 + i) * G_ + n0 + tx * 4] = o;
    }
}

// --------------------------------- enc L1 (1024 thr, 4-way k, dual-gate) ----
__global__ __launch_bounds__(1024, 4) void kB2(
    const float* __restrict__ X1,     // [CL][B][512] x-projection (+bias)
    const float* __restrict__ whhT,   // [128,512] enc_Whh1^T
    float* __restrict__ hS, float* __restrict__ cS,
    int t0, int CL)
{
    __shared__ __align__(16) float h_sh[H_ * 4];
    __shared__ __align__(16) float zp[4 * 2048];

    const int tid = threadIdx.x;
    const int j2  = tid & 255;
    const int kq  = tid >> 8;
    const int B0  = blockIdx.x * 4;

    float w0[32], w1[32];
#pragma unroll
    for (int k = 0; k < 32; k++) {
        w0[k] = whhT[(kq * 32 + k) * G_ + j2];
        w1[k] = whhT[(kq * 32 + k) * G_ + j2 + 256];
    }

    const int hid = tid & 127, bb = (tid >> 7) & 3;
    float c = 0.f;
    if (tid < 512) {
        float hv = 0.f;
        if (t0 != 0) { c = cS[(B0 + bb) * H_ + hid]; hv = hS[(B0 + bb) * H_ + hid]; }
        h_sh[hid * 4 + bb] = hv;
    }
    __syncthreads();

    const float* hb = h_sh + kq * 128;
    for (int dt = 0; dt < CL; dt++) {
        float xg0 = 0.f, xg1 = 0.f, xg2 = 0.f, xg3 = 0.f;
        if (tid < 512) {
            const size_t xb = ((size_t)dt * B_ + B0 + bb) * G_ + hid;
            xg0 = X1[xb]; xg1 = X1[xb + H_]; xg2 = X1[xb + 2*H_]; xg3 = X1[xb + 3*H_];
        }
        float a0=0.f,a1=0.f,a2=0.f,a3=0.f,e0=0.f,e1=0.f,e2=0.f,e3=0.f;
#pragma unroll
        for (int k = 0; k < 32; k++) {
            const float4 h4 = *(const float4*)&hb[k * 4];
            a0 = __fmaf_rn(h4.x, w0[k], a0); a1 = __fmaf_rn(h4.y, w0[k], a1);
            a2 = __fmaf_rn(h4.z, w0[k], a2); a3 = __fmaf_rn(h4.w, w0[k], a3);
            e0 = __fmaf_rn(h4.x, w1[k], e0); e1 = __fmaf_rn(h4.y, w1[k], e1);
            e2 = __fmaf_rn(h4.z, w1[k], e2); e3 = __fmaf_rn(h4.w, w1[k], e3);
        }
        float* zb = zp + kq * 2048;
        zb[0*G_ + j2] = a0; zb[1*G_ + j2] = a1; zb[2*G_ + j2] = a2; zb[3*G_ + j2] = a3;
        zb[0*G_ + j2+256] = e0; zb[1*G_ + j2+256] = e1; zb[2*G_ + j2+256] = e2; zb[3*G_ + j2+256] = e3;
        __syncthreads();

        if (tid < 512) {
            const int b5 = bb * G_;
            const float zi = zp[b5+hid]        + zp[2048+b5+hid]        + zp[4096+b5+hid]        + zp[6144+b5+hid]        + xg0;
            const float zf = zp[b5+hid+H_]     + zp[2048+b5+hid+H_]     + zp[4096+b5+hid+H_]     + zp[6144+b5+hid+H_]     + xg1;
            const float zg = zp[b5+hid+2*H_]   + zp[2048+b5+hid+2*H_]   + zp[4096+b5+hid+2*H_]   + zp[6144+b5+hid+2*H_]   + xg2;
            const float zo = zp[b5+hid+3*H_]   + zp[2048+b5+hid+3*H_]   + zp[4096+b5+hid+3*H_]   + zp[6144+b5+hid+3*H_]   + xg3;
            c = sigm(zf) * c + sigm(zi) * tanh_f(zg);
            h_sh[hid * 4 + bb] = sigm(zo) * tanh_f(c);
        }
        __syncthreads();
    }
    if (tid < 512) {
        hS[(B0 + bb) * H_ + hid] = h_sh[hid * 4 + bb];
        cS[(B0 + bb) * H_ + hid] = c;
    }
}

// --------------------------- decoder (head overlapped, 4 barriers/step) -----
__global__ __launch_bounds__(512, 2) void kD(
    const float* __restrict__ h1S, const float* __restrict__ c1S,
    const float* __restrict__ h2S, const float* __restrict__ c2S,
    const float* __restrict__ whh0T,  // [128][512] dec_Whh0^T (register-resident)
    const float* __restrict__ wih0,   // [512]
    const float* __restrict__ b0,
    const float* __restrict__ packD1, // [128][256][4]
    const float* __restrict__ b1,
    const float* __restrict__ wo1,    // [128][128] ORIGINAL W_out1 [hid][k]
    const float* __restrict__ bo1,
    const float* __restrict__ wo2,
    const float* __restrict__ bo2,
    float* __restrict__ out)          // [B,TGT]
{
    __shared__ __align__(16) float h1_sh[H_ * 4];
    __shared__ __align__(16) float h2_sh[H_ * 4];
    __shared__ __align__(16) float h2t[4][H_];       // [bb][hid]
    __shared__ __align__(16) float zp[2 * 2048];
    __shared__ __align__(16) float wo1s[H_ * 68];    // [hid][68]: k=64..127 half
    __shared__ float rp[8];

    const int tid = threadIdx.x;
    const int j2  = tid & 255;
    const int kh  = tid >> 8;
    const int B0  = blockIdx.x * 4;
    const int hid = tid & 127, bb = tid >> 7;

    float w0[64], w1[64];
#pragma unroll
    for (int k = 0; k < 64; k++) {
        w0[k] = whh0T[(kh * 64 + k) * G_ + j2];
        w1[k] = whh0T[(kh * 64 + k) * G_ + j2 + 256];
    }
    const float b00 = b0[j2], b01 = b0[j2 + 256];
    const float b10 = b1[j2], b11 = b1[j2 + 256];
    // x-weights for the act phase (4 gates of this thread's hid)
    const float wxi = wih0[hid], wxf = wih0[hid + H_];
    const float wxg = wih0[hid + 2*H_], wxo = wih0[hid + 3*H_];

    // head weights: k<64 in registers, k>=64 staged to LDS rows [hid][68]
    float wh[64];
#pragma unroll
    for (int k = 0; k < 64; k++) wh[k] = wo1[hid * H_ + k];
    for (int t = tid; t < H_ * 16; t += 512) {
        const int r = t >> 4, q = t & 15;
        *(float4*)&wo1s[r * 68 + q * 4] = *(const float4*)&wo1[r * H_ + 64 + q * 4];
    }

    const float wo2v = wo2[hid];
    const float bo1j = bo1[hid];
    const float bo2v = bo2[0];

    float c1 = c1S[(B0 + bb) * H_ + hid];
    float c2 = c2S[(B0 + bb) * H_ + hid];
    h1_sh[hid * 4 + bb] = h1S[(B0 + bb) * H_ + hid];
    {
        const float h2v = h2S[(B0 + bb) * H_ + hid];
        h2_sh[hid * 4 + bb] = h2v;
        h2t[bb][hid] = h2v;
    }
    if (tid < 8) rp[tid] = -0.5f * bo2v;   // so pred(step 0) = 0
    __syncthreads();

    const float* hb1 = h1_sh + kh * 256;
    const float* hb2 = h2_sh + kh * 256;
    const float* pk  = packD1 + (size_t)kh * 64 * 1024 + (size_t)j2 * 4;

    for (int s = 0; s < TGT_; s++) {
        // ===== phase 1: L0 h-dot (reg weights) + head of h2(s-1), overlapped =====
        float a0 = (kh == 0) ? b00 : 0.f, a1 = a0, a2 = a0, a3 = a0;
        float e0 = (kh == 0) ? b01 : 0.f, e1 = e0, e2 = e0, e3 = e0;
#pragma unroll
        for (int k = 0; k < 64; k++) {
            const float4 h4 = *(const float4*)&hb1[k * 4];
            a0 = __fmaf_rn(h4.x, w0[k], a0); a1 = __fmaf_rn(h4.y, w0[k], a1);
            a2 = __fmaf_rn(h4.z, w0[k], a2); a3 = __fmaf_rn(h4.w, w0[k], a3);
            e0 = __fmaf_rn(h4.x, w1[k], e0); e1 = __fmaf_rn(h4.y, w1[k], e1);
            e2 = __fmaf_rn(h4.z, w1[k], e2); e3 = __fmaf_rn(h4.w, w1[k], e3);
        }
        float* zb = zp + kh * 2048;
        zb[0*G_ + j2] = a0; zb[1*G_ + j2] = a1; zb[2*G_ + j2] = a2; zb[3*G_ + j2] = a3;
        zb[0*G_ + j2+256] = e0; zb[1*G_ + j2+256] = e1; zb[2*G_ + j2+256] = e2; zb[3*G_ + j2+256] = e3;

        // head: acc over k<64 (regs) + k>=64 (LDS rows)
        float hacc = bo1j;
#pragma unroll
        for (int kq = 0; kq < 16; kq++) {
            const float4 hq = *(const float4*)&h2t[bb][kq * 4];          // uniform
            hacc = __fmaf_rn(hq.x, wh[kq*4+0], hacc);
            hacc = __fmaf_rn(hq.y, wh[kq*4+1], hacc);
            hacc = __fmaf_rn(hq.z, wh[kq*4+2], hacc);
            hacc = __fmaf_rn(hq.w, wh[kq*4+3], hacc);
        }
#pragma unroll
        for (int kq = 0; kq < 16; kq++) {
            const float4 hq = *(const float4*)&h2t[bb][64 + kq * 4];     // uniform
            const float4 wq = *(const float4*)&wo1s[hid * 68 + kq * 4];  // lane-spread
            hacc = __fmaf_rn(hq.x, wq.x, hacc);
            hacc = __fmaf_rn(hq.y, wq.y, hacc);
            hacc = __fmaf_rn(hq.z, wq.z, hacc);
            hacc = __fmaf_rn(hq.w, wq.w, hacc);
        }
        float p = fmaxf(hacc, 0.f) * wo2v;
        p += __shfl_down(p, 32); p += __shfl_down(p, 16); p += __shfl_down(p, 8);
        p += __shfl_down(p, 4);  p += __shfl_down(p, 2);  p += __shfl_down(p, 1);
        if ((tid & 63) == 0) rp[tid >> 6] = p;
        __syncthreads();

        // ===== phase 2: L0 act (+ x-term via pred), out write =====
        {
            const float pred = rp[2 * bb] + rp[2 * bb + 1] + bo2v;
            if (hid == 0 && s > 0) out[(B0 + bb) * TGT_ + (s - 1)] = pred;
            const int b5 = bb * G_;
            const float zi = zp[b5+hid]       + zp[2048+b5+hid]       + wxi * pred;
            const float zf = zp[b5+hid+H_]    + zp[2048+b5+hid+H_]    + wxf * pred;
            const float zg = zp[b5+hid+2*H_]  + zp[2048+b5+hid+2*H_]  + wxg * pred;
            const float zo = zp[b5+hid+3*H_]  + zp[2048+b5+hid+3*H_]  + wxo * pred;
            c1 = sigm(zf) * c1 + sigm(zi) * tanh_f(zg);
            h1_sh[hid * 4 + bb] = sigm(zo) * tanh_f(c1);
        }
        __syncthreads();

        // ===== phase 3: L1 dot (L2 stream, one float4 per k per thread) =====
        float d0, d1, d2, d3, g0, g1, g2, g3;
        if (kh == 0) { d0=d1=d2=d3=b10; g0=g1=g2=g3=b11; }
        else         { d0=d1=d2=d3=0.f; g0=g1=g2=g3=0.f; }
#pragma unroll 16
        for (int k = 0; k < 64; k++) {
            const float4 wp = *(const float4*)&pk[(size_t)k * 1024];
            const float4 p4 = *(const float4*)&hb1[k * 4];
            const float4 q4 = *(const float4*)&hb2[k * 4];
            d0 = __fmaf_rn(p4.x, wp.x, __fmaf_rn(q4.x, wp.y, d0));
            d1 = __fmaf_rn(p4.y, wp.x, __fmaf_rn(q4.y, wp.y, d1));
            d2 = __fmaf_rn(p4.z, wp.x, __fmaf_rn(q4.z, wp.y, d2));
            d3 = __fmaf_rn(p4.w, wp.x, __fmaf_rn(q4.w, wp.y, d3));
            g0 = __fmaf_rn(p4.x, wp.z, __fmaf_rn(q4.x, wp.w, g0));
            g1 = __fmaf_rn(p4.y, wp.z, __fmaf_rn(q4.y, wp.w, g1));
            g2 = __fmaf_rn(p4.z, wp.z, __fmaf_rn(q4.z, wp.w, g2));
            g3 = __fmaf_rn(p4.w, wp.z, __fmaf_rn(q4.w, wp.w, g3));
        }
        zb[0*G_ + j2] = d0; zb[1*G_ + j2] = d1; zb[2*G_ + j2] = d2; zb[3*G_ + j2] = d3;
        zb[0*G_ + j2+256] = g0; zb[1*G_ + j2+256] = g1; zb[2*G_ + j2+256] = g2; zb[3*G_ + j2+256] = g3;
        __syncthreads();

        // ===== phase 4: L1 act =====
        {
            const int b5 = bb * G_;
            const float zi = zp[b5+hid]       + zp[2048+b5+hid];
            const float zf = zp[b5+hid+H_]    + zp[2048+b5+hid+H_];
            const float zg = zp[b5+hid+2*H_]  + zp[2048+b5+hid+2*H_];
            const float zo = zp[b5+hid+3*H_]  + zp[2048+b5+hid+3*H_];
            c2 = sigm(zf) * c2 + sigm(zi) * tanh_f(zg);
            const float h2v = sigm(zo) * tanh_f(c2);
            h2_sh[hid * 4 + bb] = h2v;
            h2t[bb][hid] = h2v;
        }
        __syncthreads();
    }

    // ===== epilogue: head of final h2 -> out[..][95] =====
    {
        float hacc = bo1j;
#pragma unroll
        for (int kq = 0; kq < 16; kq++) {
            const float4 hq = *(const float4*)&h2t[bb][kq * 4];
            hacc = __fmaf_rn(hq.x, wh[kq*4+0], hacc);
            hacc = __fmaf_rn(hq.y, wh[kq*4+1], hacc);
            hacc = __fmaf_rn(hq.z, wh[kq*4+2], hacc);
            hacc = __fmaf_rn(hq.w, wh[kq*4+3], hacc);
        }
#pragma unroll
        for (int kq = 0; kq < 16; kq++) {
            const float4 hq = *(const float4*)&h2t[bb][64 + kq * 4];
            const float4 wq = *(const float4*)&wo1s[hid * 68 + kq * 4];
            hacc = __fmaf_rn(hq.x, wq.x, hacc);
            hacc = __fmaf_rn(hq.y, wq.y, hacc);
            hacc = __fmaf_rn(hq.z, wq.z, hacc);
            hacc = __fmaf_rn(hq.w, wq.w, hacc);
        }
        float p = fmaxf(hacc, 0.f) * wo2v;
        p += __shfl_down(p, 32); p += __shfl_down(p, 16); p += __shfl_down(p, 8);
        p += __shfl_down(p, 4);  p += __shfl_down(p, 2);  p += __shfl_down(p, 1);
        if ((tid & 63) == 0) rp[tid >> 6] = p;
    }
    __syncthreads();
    if (tid < 4)
        out[(B0 + tid) * TGT_ + (TGT_ - 1)] = rp[2 * tid] + rp[2 * tid + 1] + bo2v;
}

// ---------------------------------------------------------------- launch ----
extern "C" void kernel_launch(void* const* d_in, const int* in_sizes, int n_in,
                              void* d_out, int out_size, void* d_ws, size_t ws_size,
                              hipStream_t stream) {
    const float* feat  = (const float*)d_in[0];
    const float* eWih0 = (const float*)d_in[1];
    const float* eWhh0 = (const float*)d_in[2];
    const float* eB0   = (const float*)d_in[3];
    const float* eWih1 = (const float*)d_in[4];
    const float* eWhh1 = (const float*)d_in[5];
    const float* eB1   = (const float*)d_in[6];
    const float* dWih0 = (const float*)d_in[7];
    const float* dWhh0 = (const float*)d_in[8];
    const float* dB0   = (const float*)d_in[9];
    const float* dWih1 = (const float*)d_in[10];
    const float* dWhh1 = (const float*)d_in[11];
    const float* dB1   = (const float*)d_in[12];
    const float* Wo1   = (const float*)d_in[13];
    const float* bo1   = (const float*)d_in[14];
    const float* Wo2   = (const float*)d_in[15];
    const float* bo2   = (const float*)d_in[16];

    const size_t SZ_BH = (size_t)B_ * H_;     // 131072
    const size_t SZ_W  = (size_t)G_ * H_;     // 65536
    const size_t fixed_f = 4 * SZ_BH + 4 * SZ_W + 2 * SZ_W + 64;

    // CL <= 42 so X1 (CL*2MB) + ys0T (CL*0.5MB) stay L3-resident
    static const int cands[] = {42, 32, 28, 24, 21, 16, 14, 12, 8, 7, 6, 4, 3, 2, 1};
    int CL = 1;
    for (int ci = 0; ci < 15; ci++) {
        const size_t need = (fixed_f + (size_t)cands[ci] * B_ * (H_ + G_)) * 4;
        if (need <= ws_size) { CL = cands[ci]; break; }
    }
    const int NC = T_ / CL;

    float* ws    = (float*)d_ws;
    float* ys0T  = ws;                                   // [CL][128][1024]
    float* X1    = ys0T + (size_t)CL * B_ * H_;          // [CL][1024][512]
    float* h1S   = X1 + (size_t)CL * B_ * G_;
    float* c1S   = h1S + SZ_BH;
    float* h2S   = c1S + SZ_BH;
    float* c2S   = h2S + SZ_BH;
    float* wtE0  = c2S + SZ_BH;
    float* wtE1x = wtE0 + SZ_W;
    float* wtE1h = wtE1x + SZ_W;
    float* wtD0  = wtE1h + SZ_W;
    float* wtD1p = wtD0 + SZ_W;            // [128][256][4]

    PrepArgs pa;
    pa.t_src[0] = eWhh0; pa.t_dst[0] = wtE0;
    pa.t_src[1] = eWih1; pa.t_dst[1] = wtE1x;
    pa.t_src[2] = eWhh1; pa.t_dst[2] = wtE1h;
    pa.t_src[3] = dWhh0; pa.t_dst[3] = wtD0;
    pa.d1x = dWih1; pa.d1h = dWhh1; pa.pack = wtD1p;
    kPrep<<<5, 256, 0, stream>>>(pa);

    for (int c = 0; c < NC; c++) {
        const int t0 = c * CL;
        kA<<<NBLK_, 1024, 0, stream>>>(feat, wtE0, eWih0, eB0, ys0T, h1S, c1S, t0, CL);
        kX<<<dim3(8, 8, CL), 256, 0, stream>>>(ys0T, wtE1x, eB1, X1);
        kB2<<<NBLK_, 1024, 0, stream>>>(X1, wtE1h, h2S, c2S, t0, CL);
    }
    kD<<<NBLK_, 512, 0, stream>>>(h1S, c1S, h2S, c2S,
                                  wtD0, dWih0, dB0,
                                  wtD1p, dB1,
                                  Wo1, bo1, Wo2, bo2,
                                  (float*)d_out);
}

// Round 7
// 5077.685 us; speedup vs baseline: 1.1399x; 1.1399x over previous
//
#include <hip/hip_runtime.h>

// Seq2SeqLSTMForecaster on MI355X — round 7: QUAD-GATE recurrent kernels.
// The recurrent kernels were LDS-instruction-bound: uniform h-broadcast count
// = waves × k/thread is invariant under split-k (round-6 lesson). Quad-gate
// (each thread owns gates j4, j4+128, +256, +384 = the i,f,g,o of hid j4)
// gives 16 FMA per uniform b128 read -> dot LDS instr halved below the VALU
// floor, and the dot thread (j4,kq) IS the act thread (hid,bb).
//  - kA : enc L0, quad-gate 4-way-k, 512 thr; x-term+bias folded into act.
//  - kX : fp32 tiled GEMM (unchanged).
//  - kB2: enc L1, quad-gate 4-way-k, X1 prefetched before dot.
//  - kD : decoder, quad-gate both dots; L0 weights in regs (128 VGPR), L1
//         streamed via [k][j4][8] pack (32 contiguous B per thread per k);
//         head all-LDS rows [hid][132] lane-spread b128; pred-overlap kept.

#define B_    1024
#define T_    672
#define H_    128
#define G_    512      // 4*H
#define TGT_  96
#define NBLK_ 256

__device__ __forceinline__ float sigm(float x)   { return 1.f / (1.f + __expf(-x)); }
__device__ __forceinline__ float tanh_f(float x) { return 1.f - 2.f / (1.f + __expf(2.f * x)); }

// ---------------------------------------------------------------- prep ------
struct PrepArgs {
    const float* t_src[4];   // eWhh0, eWih1, eWhh1, dWhh0 -> [128,512]
    float*       t_dst[4];
    const float* d1x;  const float* d1h;  float* pack;   // dec L1 8-wide pack
};

__global__ void kPrep(PrepArgs a) {
    const int m = blockIdx.x;
    if (m < 4) {
        for (int i = threadIdx.x; i < G_ * H_; i += blockDim.x) {
            const int j = i >> 7, k = i & 127;
            a.t_dst[m][k * G_ + j] = a.t_src[m][i];
        }
    } else {
        // pack[(k*128 + j4)*8 + g]   = dWih1[j4+128g][k]  (g=0..3)
        // pack[(k*128 + j4)*8 + 4+g] = dWhh1[j4+128g][k]
        for (int i = threadIdx.x; i < H_ * H_; i += blockDim.x) {
            const int k = i >> 7, j4 = i & 127;
            float* p = a.pack + ((size_t)k * H_ + j4) * 8;
#pragma unroll
            for (int g = 0; g < 4; g++) {
                p[g]     = a.d1x[(j4 + 128 * g) * H_ + k];
                p[4 + g] = a.d1h[(j4 + 128 * g) * H_ + k];
            }
        }
    }
}

// --------------------------------- enc L0 (quad-gate, 4-way k, 512 thr) -----
__global__ __launch_bounds__(512, 2) void kA(
    const float* __restrict__ feat,   // [B,T]
    const float* __restrict__ whhT,   // [128,512] enc_Whh0^T
    const float* __restrict__ wih0,   // [512]
    const float* __restrict__ bias,   // [512]
    float* __restrict__ ys0T,         // [CL][128][1024] k-major
    float* __restrict__ hS, float* __restrict__ cS,
    int t0, int CL)
{
    __shared__ __align__(16) float h_sh[H_ * 4];     // [hid][bb]
    __shared__ __align__(16) float zp[4 * 2048];     // [kq][batch][gate]
    __shared__ __align__(16) float f_sh[84 * 4];

    const int tid = threadIdx.x;
    const int hid = tid & 127;        // = j4 (gate group) = act hid
    const int bb  = tid >> 7;         // = kq (k-quarter)  = act batch
    const int B0  = blockIdx.x * 4;

    float w[4][32];
#pragma unroll
    for (int g = 0; g < 4; g++)
#pragma unroll
        for (int k = 0; k < 32; k++)
            w[g][k] = whhT[(bb * 32 + k) * G_ + hid + 128 * g];

    const float bi = bias[hid],           bf = bias[hid + 128];
    const float bg = bias[hid + 256],     bo = bias[hid + 384];
    const float wxi = wih0[hid],          wxf = wih0[hid + 128];
    const float wxg = wih0[hid + 256],    wxo = wih0[hid + 384];

    for (int i = tid; i < CL * 4; i += 512)
        f_sh[i] = feat[(B0 + (i & 3)) * T_ + t0 + (i >> 2)];

    float c = 0.f;
    {
        float hv = 0.f;
        if (t0 != 0) { c = cS[(B0 + bb) * H_ + hid]; hv = hS[(B0 + bb) * H_ + hid]; }
        h_sh[hid * 4 + bb] = hv;
    }
    __syncthreads();

    const float* hb = h_sh + bb * 128;   // k-range bb*32..+31, [k][batch]
    for (int dt = 0; dt < CL; dt++) {
        if (dt > 0)
            ys0T[((size_t)(dt - 1) * H_ + (tid >> 2)) * B_ + B0 + (tid & 3)] = h_sh[tid];

        float a[4][4] = {};
#pragma unroll
        for (int k = 0; k < 32; k++) {
            const float4 h4 = *(const float4*)&hb[k * 4];   // uniform broadcast
#pragma unroll
            for (int g = 0; g < 4; g++) {
                a[g][0] = __fmaf_rn(h4.x, w[g][k], a[g][0]);
                a[g][1] = __fmaf_rn(h4.y, w[g][k], a[g][1]);
                a[g][2] = __fmaf_rn(h4.z, w[g][k], a[g][2]);
                a[g][3] = __fmaf_rn(h4.w, w[g][k], a[g][3]);
            }
        }
#pragma unroll
        for (int g = 0; g < 4; g++)
#pragma unroll
            for (int b = 0; b < 4; b++)
                zp[bb * 2048 + b * 512 + hid + 128 * g] = a[g][b];
        __syncthreads();

        {
            const float x = f_sh[dt * 4 + bb];
            const int base = bb * 512 + hid;
            float zi = __fmaf_rn(wxi, x, bi);
            float zf = __fmaf_rn(wxf, x, bf);
            float zg = __fmaf_rn(wxg, x, bg);
            float zo = __fmaf_rn(wxo, x, bo);
#pragma unroll
            for (int q = 0; q < 4; q++) {
                zi += zp[q * 2048 + base];
                zf += zp[q * 2048 + base + 128];
                zg += zp[q * 2048 + base + 256];
                zo += zp[q * 2048 + base + 384];
            }
            c = sigm(zf) * c + sigm(zi) * tanh_f(zg);
            h_sh[hid * 4 + bb] = sigm(zo) * tanh_f(c);
        }
        __syncthreads();
    }
    ys0T[((size_t)(CL - 1) * H_ + (tid >> 2)) * B_ + B0 + (tid & 3)] = h_sh[tid];
    hS[(B0 + bb) * H_ + hid] = h_sh[hid * 4 + bb];
    cS[(B0 + bb) * H_ + hid] = c;
}

// ------------------------------------------------- X1 GEMM (fp32 tiled) -----
__global__ __launch_bounds__(256, 3) void kX(
    const float* __restrict__ ys0T,   // [CL][128][1024]
    const float* __restrict__ wT,     // [128][512]
    const float* __restrict__ bias,   // [512]
    float* __restrict__ X1)           // [CL][1024][512]
{
    __shared__ __align__(16) float As[64][132];
    __shared__ __align__(16) float Bs[64][68];

    const int tid = threadIdx.x;
    const int m0 = blockIdx.x * 128;
    const int n0 = blockIdx.y * 64;
    const int dt = blockIdx.z;
    const float* A = ys0T + (size_t)dt * H_ * B_;

    const int tx = tid & 15, ty = tid >> 4;
    float acc[8][4] = {};

#pragma unroll
    for (int ks = 0; ks < 2; ks++) {
        if (ks) __syncthreads();
        for (int t = tid; t < 64 * 32; t += 256) {
            const int r = t >> 5, q = t & 31;
            *(float4*)&As[r][q * 4] = *(const float4*)&A[(size_t)(ks * 64 + r) * B_ + m0 + q * 4];
        }
        for (int t = tid; t < 64 * 16; t += 256) {
            const int r = t >> 4, q = t & 15;
            *(float4*)&Bs[r][q * 4] = *(const float4*)&wT[(size_t)(ks * 64 + r) * G_ + n0 + q * 4];
        }
        __syncthreads();

#pragma unroll 4
        for (int k = 0; k < 64; k++) {
            float av[8];
            *(float4*)&av[0] = *(const float4*)&As[k][ty * 8];
            *(float4*)&av[4] = *(const float4*)&As[k][ty * 8 + 4];
            const float4 bv = *(const float4*)&Bs[k][tx * 4];
#pragma unroll
            for (int i = 0; i < 8; i++) {
                acc[i][0] = __fmaf_rn(av[i], bv.x, acc[i][0]);
                acc[i][1] = __fmaf_rn(av[i], bv.y, acc[i][1]);
                acc[i][2] = __fmaf_rn(av[i], bv.z, acc[i][2]);
                acc[i][3] = __fmaf_rn(av[i], bv.w, acc[i][3]);
            }
        }
    }

    const float4 bvb = *(const float4*)&bias[n0 + tx * 4];
#pragma unroll
    for (int i = 0; i < 8; i++) {
        float4 o;
        o.x = acc[i][0] + bvb.x; o.y = acc[i][1] + bvb.y;
        o.z = acc[i][2] + bvb.z; o.w = acc[i][3] + bvb.w;
        *(float4*)&X1[((size_t)dt * B_ + m0 + ty * 8 + i) * G_ + n0 + tx * 4] = o;
    }
}

// --------------------------------- enc L1 (quad-gate, 4-way k, 512 thr) -----
__global__ __launch_bounds__(512, 2) void kB2(
    const float* __restrict__ X1,     // [CL][B][512] x-projection (+bias)
    const float* __restrict__ whhT,   // [128,512] enc_Whh1^T
    float* __restrict__ hS, float* __restrict__ cS,
    int t0, int CL)
{
    __shared__ __align__(16) float h_sh[H_ * 4];
    __shared__ __align__(16) float zp[4 * 2048];

    const int tid = threadIdx.x;
    const int hid = tid & 127;
    const int bb  = tid >> 7;
    const int B0  = blockIdx.x * 4;

    float w[4][32];
#pragma unroll
    for (int g = 0; g < 4; g++)
#pragma unroll
        for (int k = 0; k < 32; k++)
            w[g][k] = whhT[(bb * 32 + k) * G_ + hid + 128 * g];

    float c = 0.f;
    {
        float hv = 0.f;
        if (t0 != 0) { c = cS[(B0 + bb) * H_ + hid]; hv = hS[(B0 + bb) * H_ + hid]; }
        h_sh[hid * 4 + bb] = hv;
    }
    __syncthreads();

    const float* hb = h_sh + bb * 128;
    for (int dt = 0; dt < CL; dt++) {
        // prefetch this thread's x-projection (hides L2/L3 latency under dot)
        const size_t xb = ((size_t)dt * B_ + B0 + bb) * G_ + hid;
        const float xg0 = X1[xb];
        const float xg1 = X1[xb + 128];
        const float xg2 = X1[xb + 256];
        const float xg3 = X1[xb + 384];

        float a[4][4] = {};
#pragma unroll
        for (int k = 0; k < 32; k++) {
            const float4 h4 = *(const float4*)&hb[k * 4];
#pragma unroll
            for (int g = 0; g < 4; g++) {
                a[g][0] = __fmaf_rn(h4.x, w[g][k], a[g][0]);
                a[g][1] = __fmaf_rn(h4.y, w[g][k], a[g][1]);
                a[g][2] = __fmaf_rn(h4.z, w[g][k], a[g][2]);
                a[g][3] = __fmaf_rn(h4.w, w[g][k], a[g][3]);
            }
        }
#pragma unroll
        for (int g = 0; g < 4; g++)
#pragma unroll
            for (int b = 0; b < 4; b++)
                zp[bb * 2048 + b * 512 + hid + 128 * g] = a[g][b];
        __syncthreads();

        {
            const int base = bb * 512 + hid;
            float zi = xg0, zf = xg1, zg = xg2, zo = xg3;
#pragma unroll
            for (int q = 0; q < 4; q++) {
                zi += zp[q * 2048 + base];
                zf += zp[q * 2048 + base + 128];
                zg += zp[q * 2048 + base + 256];
                zo += zp[q * 2048 + base + 384];
            }
            c = sigm(zf) * c + sigm(zi) * tanh_f(zg);
            h_sh[hid * 4 + bb] = sigm(zo) * tanh_f(c);
        }
        __syncthreads();
    }
    hS[(B0 + bb) * H_ + hid] = h_sh[hid * 4 + bb];
    cS[(B0 + bb) * H_ + hid] = c;
}

// ------------------------------------------- decoder (quad-gate both dots) --
__global__ __launch_bounds__(512, 2) void kD(
    const float* __restrict__ h1S, const float* __restrict__ c1S,
    const float* __restrict__ h2S, const float* __restrict__ c2S,
    const float* __restrict__ whh0T,  // [128][512] dec_Whh0^T (register-resident)
    const float* __restrict__ wih0,   // [512]
    const float* __restrict__ b0,
    const float* __restrict__ packD1, // [128][128][8]
    const float* __restrict__ b1,
    const float* __restrict__ wo1,    // [128][128] W_out1 [hid][k] -> LDS rows
    const float* __restrict__ bo1,
    const float* __restrict__ wo2,
    const float* __restrict__ bo2,
    float* __restrict__ out)          // [B,TGT]
{
    __shared__ __align__(16) float h1_sh[H_ * 4];
    __shared__ __align__(16) float h2_sh[H_ * 4];
    __shared__ __align__(16) float h2t[4][H_];       // [bb][hid]
    __shared__ __align__(16) float zp[4 * 2048];
    __shared__ __align__(16) float wo1s[H_ * 132];   // rows [hid][k], pad 132
    __shared__ float rp[8];

    const int tid = threadIdx.x;
    const int hid = tid & 127;        // gate group / act hid
    const int bb  = tid >> 7;         // k-quarter / act batch
    const int B0  = blockIdx.x * 4;

    float w0[4][32];
#pragma unroll
    for (int g = 0; g < 4; g++)
#pragma unroll
        for (int k = 0; k < 32; k++)
            w0[g][k] = whh0T[(bb * 32 + k) * G_ + hid + 128 * g];

    const float b0i = b0[hid],        b0f = b0[hid + 128];
    const float b0g = b0[hid + 256],  b0o = b0[hid + 384];
    const float wxi = wih0[hid],      wxf = wih0[hid + 128];
    const float wxg = wih0[hid + 256], wxo = wih0[hid + 384];
    const float b1i = b1[hid],        b1f = b1[hid + 128];
    const float b1g = b1[hid + 256],  b1o = b1[hid + 384];

    // stage W_out1 rows [hid][k] into padded LDS rows (b128 copies)
    for (int t = tid; t < H_ * 32; t += 512) {
        const int r = t >> 5, q = t & 31;
        *(float4*)&wo1s[r * 132 + q * 4] = *(const float4*)&wo1[r * H_ + q * 4];
    }

    const float wo2v = wo2[hid];
    const float bo1j = bo1[hid];
    const float bo2v = bo2[0];

    float c1 = c1S[(B0 + bb) * H_ + hid];
    float c2 = c2S[(B0 + bb) * H_ + hid];
    h1_sh[hid * 4 + bb] = h1S[(B0 + bb) * H_ + hid];
    {
        const float h2v = h2S[(B0 + bb) * H_ + hid];
        h2_sh[hid * 4 + bb] = h2v;
        h2t[bb][hid] = h2v;
    }
    if (tid < 8) rp[tid] = -0.5f * bo2v;   // so pred(step 0) = 0
    __syncthreads();

    const float* hb1 = h1_sh + bb * 128;
    const float* hb2 = h2_sh + bb * 128;
    const float* pk  = packD1 + ((size_t)bb * 32 * H_ + hid) * 8;

    for (int s = 0; s < TGT_; s++) {
        // ===== phase 1: L0 h-dot (reg weights) + head of h2(s-1), overlapped =====
        {
            float a[4][4] = {};
#pragma unroll
            for (int k = 0; k < 32; k++) {
                const float4 h4 = *(const float4*)&hb1[k * 4];
#pragma unroll
                for (int g = 0; g < 4; g++) {
                    a[g][0] = __fmaf_rn(h4.x, w0[g][k], a[g][0]);
                    a[g][1] = __fmaf_rn(h4.y, w0[g][k], a[g][1]);
                    a[g][2] = __fmaf_rn(h4.z, w0[g][k], a[g][2]);
                    a[g][3] = __fmaf_rn(h4.w, w0[g][k], a[g][3]);
                }
            }
#pragma unroll
            for (int g = 0; g < 4; g++)
#pragma unroll
                for (int b = 0; b < 4; b++)
                    zp[bb * 2048 + b * 512 + hid + 128 * g] = a[g][b];
        }
        // head on previous h2
        {
            float hacc = bo1j;
#pragma unroll
            for (int q = 0; q < 32; q++) {
                const float4 hq = *(const float4*)&h2t[bb][q * 4];          // uniform
                const float4 wq = *(const float4*)&wo1s[hid * 132 + q * 4]; // lane-spread
                hacc = __fmaf_rn(hq.x, wq.x, hacc);
                hacc = __fmaf_rn(hq.y, wq.y, hacc);
                hacc = __fmaf_rn(hq.z, wq.z, hacc);
                hacc = __fmaf_rn(hq.w, wq.w, hacc);
            }
            float p = fmaxf(hacc, 0.f) * wo2v;
            p += __shfl_down(p, 32); p += __shfl_down(p, 16); p += __shfl_down(p, 8);
            p += __shfl_down(p, 4);  p += __shfl_down(p, 2);  p += __shfl_down(p, 1);
            if ((tid & 63) == 0) rp[tid >> 6] = p;   // wave w covers bb = w>>1
        }
        __syncthreads();

        // ===== phase 2: L0 act (+ x-term via pred), out write =====
        {
            const float pred = rp[2 * bb] + rp[2 * bb + 1] + bo2v;
            if (hid == 0 && s > 0) out[(B0 + bb) * TGT_ + (s - 1)] = pred;
            const int base = bb * 512 + hid;
            float zi = __fmaf_rn(wxi, pred, b0i);
            float zf = __fmaf_rn(wxf, pred, b0f);
            float zg = __fmaf_rn(wxg, pred, b0g);
            float zo = __fmaf_rn(wxo, pred, b0o);
#pragma unroll
            for (int q = 0; q < 4; q++) {
                zi += zp[q * 2048 + base];
                zf += zp[q * 2048 + base + 128];
                zg += zp[q * 2048 + base + 256];
                zo += zp[q * 2048 + base + 384];
            }
            c1 = sigm(zf) * c1 + sigm(zi) * tanh_f(zg);
            h1_sh[hid * 4 + bb] = sigm(zo) * tanh_f(c1);
        }
        __syncthreads();

        // ===== phase 3: L1 dot (L2 stream: 32 contiguous B per thread per k) =====
        {
            float d[4][4] = {};
#pragma unroll 8
            for (int k = 0; k < 32; k++) {
                const float4 wi = *(const float4*)&pk[(size_t)k * 1024];
                const float4 wh = *(const float4*)&pk[(size_t)k * 1024 + 4];
                const float4 p1 = *(const float4*)&hb1[k * 4];
                const float4 p2 = *(const float4*)&hb2[k * 4];
                d[0][0] = __fmaf_rn(p1.x, wi.x, __fmaf_rn(p2.x, wh.x, d[0][0]));
                d[0][1] = __fmaf_rn(p1.y, wi.x, __fmaf_rn(p2.y, wh.x, d[0][1]));
                d[0][2] = __fmaf_rn(p1.z, wi.x, __fmaf_rn(p2.z, wh.x, d[0][2]));
                d[0][3] = __fmaf_rn(p1.w, wi.x, __fmaf_rn(p2.w, wh.x, d[0][3]));
                d[1][0] = __fmaf_rn(p1.x, wi.y, __fmaf_rn(p2.x, wh.y, d[1][0]));
                d[1][1] = __fmaf_rn(p1.y, wi.y, __fmaf_rn(p2.y, wh.y, d[1][1]));
                d[1][2] = __fmaf_rn(p1.z, wi.y, __fmaf_rn(p2.z, wh.y, d[1][2]));
                d[1][3] = __fmaf_rn(p1.w, wi.y, __fmaf_rn(p2.w, wh.y, d[1][3]));
                d[2][0] = __fmaf_rn(p1.x, wi.z, __fmaf_rn(p2.x, wh.z, d[2][0]));
                d[2][1] = __fmaf_rn(p1.y, wi.z, __fmaf_rn(p2.y, wh.z, d[2][1]));
                d[2][2] = __fmaf_rn(p1.z, wi.z, __fmaf_rn(p2.z, wh.z, d[2][2]));
                d[2][3] = __fmaf_rn(p1.w, wi.z, __fmaf_rn(p2.w, wh.z, d[2][3]));
                d[3][0] = __fmaf_rn(p1.x, wi.w, __fmaf_rn(p2.x, wh.w, d[3][0]));
                d[3][1] = __fmaf_rn(p1.y, wi.w, __fmaf_rn(p2.y, wh.w, d[3][1]));
                d[3][2] = __fmaf_rn(p1.z, wi.w, __fmaf_rn(p2.z, wh.w, d[3][2]));
                d[3][3] = __fmaf_rn(p1.w, wi.w, __fmaf_rn(p2.w, wh.w, d[3][3]));
            }
#pragma unroll
            for (int g = 0; g < 4; g++)
#pragma unroll
                for (int b = 0; b < 4; b++)
                    zp[bb * 2048 + b * 512 + hid + 128 * g] = d[g][b];
        }
        __syncthreads();

        // ===== phase 4: L1 act =====
        {
            const int base = bb * 512 + hid;
            float zi = b1i, zf = b1f, zg = b1g, zo = b1o;
#pragma unroll
            for (int q = 0; q < 4; q++) {
                zi += zp[q * 2048 + base];
                zf += zp[q * 2048 + base + 128];
                zg += zp[q * 2048 + base + 256];
                zo += zp[q * 2048 + base + 384];
            }
            c2 = sigm(zf) * c2 + sigm(zi) * tanh_f(zg);
            const float h2v = sigm(zo) * tanh_f(c2);
            h2_sh[hid * 4 + bb] = h2v;
            h2t[bb][hid] = h2v;
        }
        __syncthreads();
    }

    // ===== epilogue: head of final h2 -> out[..][95] =====
    {
        float hacc = bo1j;
#pragma unroll
        for (int q = 0; q < 32; q++) {
            const float4 hq = *(const float4*)&h2t[bb][q * 4];
            const float4 wq = *(const float4*)&wo1s[hid * 132 + q * 4];
            hacc = __fmaf_rn(hq.x, wq.x, hacc);
            hacc = __fmaf_rn(hq.y, wq.y, hacc);
            hacc = __fmaf_rn(hq.z, wq.z, hacc);
            hacc = __fmaf_rn(hq.w, wq.w, hacc);
        }
        float p = fmaxf(hacc, 0.f) * wo2v;
        p += __shfl_down(p, 32); p += __shfl_down(p, 16); p += __shfl_down(p, 8);
        p += __shfl_down(p, 4);  p += __shfl_down(p, 2);  p += __shfl_down(p, 1);
        if ((tid & 63) == 0) rp[tid >> 6] = p;
    }
    __syncthreads();
    if (tid < 4)
        out[(B0 + tid) * TGT_ + (TGT_ - 1)] = rp[2 * tid] + rp[2 * tid + 1] + bo2v;
}

// ---------------------------------------------------------------- launch ----
extern "C" void kernel_launch(void* const* d_in, const int* in_sizes, int n_in,
                              void* d_out, int out_size, void* d_ws, size_t ws_size,
                              hipStream_t stream) {
    const float* feat  = (const float*)d_in[0];
    const float* eWih0 = (const float*)d_in[1];
    const float* eWhh0 = (const float*)d_in[2];
    const float* eB0   = (const float*)d_in[3];
    const float* eWih1 = (const float*)d_in[4];
    const float* eWhh1 = (const float*)d_in[5];
    const float* eB1   = (const float*)d_in[6];
    const float* dWih0 = (const float*)d_in[7];
    const float* dWhh0 = (const float*)d_in[8];
    const float* dB0   = (const float*)d_in[9];
    const float* dWih1 = (const float*)d_in[10];
    const float* dWhh1 = (const float*)d_in[11];
    const float* dB1   = (const float*)d_in[12];
    const float* Wo1   = (const float*)d_in[13];
    const float* bo1   = (const float*)d_in[14];
    const float* Wo2   = (const float*)d_in[15];
    const float* bo2   = (const float*)d_in[16];

    const size_t SZ_BH = (size_t)B_ * H_;     // 131072
    const size_t SZ_W  = (size_t)G_ * H_;     // 65536
    const size_t fixed_f = 4 * SZ_BH + 4 * SZ_W + 2 * SZ_W + 64;

    // CL <= 42 so X1 (CL*2MB) + ys0T (CL*0.5MB) stay L3-resident
    static const int cands[] = {42, 32, 28, 24, 21, 16, 14, 12, 8, 7, 6, 4, 3, 2, 1};
    int CL = 1;
    for (int ci = 0; ci < 15; ci++) {
        const size_t need = (fixed_f + (size_t)cands[ci] * B_ * (H_ + G_)) * 4;
        if (need <= ws_size) { CL = cands[ci]; break; }
    }
    const int NC = T_ / CL;

    float* ws    = (float*)d_ws;
    float* ys0T  = ws;                                   // [CL][128][1024]
    float* X1    = ys0T + (size_t)CL * B_ * H_;          // [CL][1024][512]
    float* h1S   = X1 + (size_t)CL * B_ * G_;
    float* c1S   = h1S + SZ_BH;
    float* h2S   = c1S + SZ_BH;
    float* c2S   = h2S + SZ_BH;
    float* wtE0  = c2S + SZ_BH;
    float* wtE1x = wtE0 + SZ_W;
    float* wtE1h = wtE1x + SZ_W;
    float* wtD0  = wtE1h + SZ_W;
    float* wtD1p = wtD0 + SZ_W;            // [128][128][8] = 2*SZ_W

    PrepArgs pa;
    pa.t_src[0] = eWhh0; pa.t_dst[0] = wtE0;
    pa.t_src[1] = eWih1; pa.t_dst[1] = wtE1x;
    pa.t_src[2] = eWhh1; pa.t_dst[2] = wtE1h;
    pa.t_src[3] = dWhh0; pa.t_dst[3] = wtD0;
    pa.d1x = dWih1; pa.d1h = dWhh1; pa.pack = wtD1p;
    kPrep<<<5, 256, 0, stream>>>(pa);

    for (int c = 0; c < NC; c++) {
        const int t0 = c * CL;
        kA<<<NBLK_, 512, 0, stream>>>(feat, wtE0, eWih0, eB0, ys0T, h1S, c1S, t0, CL);
        kX<<<dim3(8, 8, CL), 256, 0, stream>>>(ys0T, wtE1x, eB1, X1);
        kB2<<<NBLK_, 512, 0, stream>>>(X1, wtE1h, h2S, c2S, t0, CL);
    }
    kD<<<NBLK_, 512, 0, stream>>>(h1S, c1S, h2S, c2S,
                                  wtD0, dWih0, dB0,
                                  wtD1p, dB1,
                                  Wo1, bo1, Wo2, bo2,
                                  (float*)d_out);
}